// Round 1
// baseline (1739.960 us; speedup 1.0000x reference)
//
#include <hip/hip_runtime.h>

#define N_DATA    500000
#define FEAT_DIM  512
#define NUM_CLASS 10000
#define BATCH     8192
#define MOMENTUM  0.9f

// -------- Kernel 1/2: vectorized grid-stride copy (float4) --------
__global__ __launch_bounds__(256) void copy_f4_kernel(const float4* __restrict__ src,
                                                      float4* __restrict__ dst,
                                                      long long n4) {
    long long i = (long long)blockIdx.x * blockDim.x + threadIdx.x;
    long long stride = (long long)gridDim.x * blockDim.x;
    for (; i < n4; i += stride) {
        dst[i] = src[i];
    }
}

// -------- Kernel 3: fused gather + blend + L2-normalize + scatter + class atomicAdd --------
// One block per batch row. 128 threads * float4 = 512 floats per row.
__global__ __launch_bounds__(128) void update_kernel(const float4* __restrict__ batch,   // [BATCH, 128] as float4
                                                     const float4* __restrict__ lat,     // [N_DATA, 128]
                                                     const int*    __restrict__ targets, // [BATCH]
                                                     const int*    __restrict__ idx,     // [BATCH]
                                                     float4*       __restrict__ out_lat, // [N_DATA, 128]
                                                     float*        __restrict__ out_cls) // [NUM_CLASS, 512]
{
    const int row = blockIdx.x;    // 0..BATCH-1
    const int t   = threadIdx.x;   // 0..127

    const int src_row = idx[row];
    const int cls     = targets[row];

    const float4 b = batch[(long long)row * 128 + t];
    const float4 m = lat[(long long)src_row * 128 + t];

    float4 v;
    v.x = m.x * (1.0f - MOMENTUM) + b.x * MOMENTUM;
    v.y = m.y * (1.0f - MOMENTUM) + b.y * MOMENTUM;
    v.z = m.z * (1.0f - MOMENTUM) + b.z * MOMENTUM;
    v.w = m.w * (1.0f - MOMENTUM) + b.w * MOMENTUM;

    float ss = v.x * v.x + v.y * v.y + v.z * v.z + v.w * v.w;

    // wave-64 reduction
    #pragma unroll
    for (int off = 32; off > 0; off >>= 1) {
        ss += __shfl_down(ss, off, 64);
    }

    __shared__ float partial[2];
    if ((t & 63) == 0) partial[t >> 6] = ss;
    __syncthreads();
    const float total = partial[0] + partial[1];
    const float inv = 1.0f / sqrtf(total);

    v.x *= inv; v.y *= inv; v.z *= inv; v.w *= inv;

    // scatter normalized row into output bank (overwrites the plain copy)
    out_lat[(long long)src_row * 128 + t] = v;

    // per-class segment sum: 4 float atomics per thread, low contention
    float* cp = out_cls + (long long)cls * FEAT_DIM + t * 4;
    atomicAdd(cp + 0, v.x);
    atomicAdd(cp + 1, v.y);
    atomicAdd(cp + 2, v.z);
    atomicAdd(cp + 3, v.w);
}

extern "C" void kernel_launch(void* const* d_in, const int* in_sizes, int n_in,
                              void* d_out, int out_size, void* d_ws, size_t ws_size,
                              hipStream_t stream) {
    const float* batch    = (const float*)d_in[0];  // [BATCH, FEAT_DIM]
    const float* lat      = (const float*)d_in[1];  // [N_DATA, FEAT_DIM]
    const float* cls_sums = (const float*)d_in[2];  // [NUM_CLASS, FEAT_DIM]
    const int*   targets  = (const int*)d_in[3];    // [BATCH]
    const int*   idx      = (const int*)d_in[4];    // [BATCH]

    float* out_lat = (float*)d_out;                              // [N_DATA, FEAT_DIM]
    float* out_cls = out_lat + (long long)N_DATA * FEAT_DIM;     // [NUM_CLASS, FEAT_DIM]

    // 1) copy lat_memory -> out_lat  (the roofline term: 2.05 GB traffic)
    {
        long long n4 = (long long)N_DATA * FEAT_DIM / 4;  // 64,000,000
        int blocks = 8192;
        copy_f4_kernel<<<blocks, 256, 0, stream>>>((const float4*)lat, (float4*)out_lat, n4);
    }

    // 2) copy class_sums -> out_cls (41 MB)
    {
        long long n4 = (long long)NUM_CLASS * FEAT_DIM / 4;  // 1,280,000
        int blocks = 2560;
        copy_f4_kernel<<<blocks, 256, 0, stream>>>((const float4*)cls_sums, (float4*)out_cls, n4);
    }

    // 3) fused gather/blend/normalize/scatter/segment-sum
    update_kernel<<<BATCH, 128, 0, stream>>>((const float4*)batch, (const float4*)lat,
                                             targets, idx,
                                             (float4*)out_lat, out_cls);
}